// Round 17
// baseline (646.142 us; speedup 1.0000x reference)
//
#include <hip/hip_runtime.h>
#include <stdint.h>

// Problem constants (n=1, c=32, h=w=128, p=3)
#define NPT    16384        // points (h*w)
#define KD     288          // c*p*p
#define KE     576          // per-point row: [hi(288) | lo(288)] f16
#define KEP    584          // padded LDS row (extract): bank stride 4 -> 4-way
#define NWIN   9            // 9 merged K-windows of 32 (hi+lo staged together)

typedef _Float16 f16;
typedef __attribute__((ext_vector_type(8))) _Float16 half8;
typedef __attribute__((ext_vector_type(16))) float floatx16;

#define AS1(p) ((const __attribute__((address_space(1))) uint32_t*)(p))
#define AS3(p) ((__attribute__((address_space(3))) uint32_t*)(p))

// -------- patch extraction + fp32->2xf16 split + fused norms/init ------------
// Block = 32 consecutive points, 256 threads. LDS rows padded to KEP=584
// halves: byte stride 1168 -> dword stride 292 -> bank stride 4 (4-way
// conflict) vs the unpadded 1152-B stride's bank-0-for-all (32-way, the
// reason extract ran ~58 us vs ~6 us roofline).
__global__ __launch_bounds__(256)
void extract_split_kernel(const float* __restrict__ src,
                          const float* __restrict__ tgt,
                          f16* __restrict__ Aext,
                          f16* __restrict__ Bext,
                          float* __restrict__ rq,
                          float* __restrict__ rp,
                          unsigned long long* __restrict__ best) {
  __shared__ f16 bufA[32 * KEP];      // 36.5 KB
  __shared__ f16 bufB[32 * KEP];      // 36.5 KB
  __shared__ double prtA[8][32];
  __shared__ double prtB[8][32];

  const int tid = threadIdx.x;
  const int p  = tid & 31;            // local point
  const int cg = tid >> 5;            // channel group 0..7
  const int point = blockIdx.x * 32 + p;
  const int y = point >> 7, x = point & 127;

  double sq = 0.0, sp_ = 0.0;
#pragma unroll
  for (int cc = 0; cc < 4; ++cc) {
    const int c = cg * 4 + cc;
#pragma unroll
    for (int dy = 0; dy < 3; ++dy) {
      int yy = y + dy - 1; yy = yy < 0 ? 0 : (yy > 127 ? 127 : yy);
#pragma unroll
      for (int dx = 0; dx < 3; ++dx) {
        int xx = x + dx - 1; xx = xx < 0 ? 0 : (xx > 127 ? 127 : xx);
        const int k = c * 9 + dy * 3 + dx;
        const int m = (c << 14) + (yy << 7) + xx;
        float v = src[m];
        sq += (double)v * (double)v;
        f16 h = (f16)v;
        bufA[p * KEP + k] = h;
        bufA[p * KEP + KD + k] = (f16)(v - (float)h);
        v = tgt[m];
        sp_ += (double)v * (double)v;
        h = (f16)v;
        bufB[p * KEP + k] = h;
        bufB[p * KEP + KD + k] = (f16)(v - (float)h);
      }
    }
  }
  prtA[cg][p] = sq;
  prtB[cg][p] = sp_;
  __syncthreads();

  if (tid < 32) {
    double s = 0.0;
#pragma unroll
    for (int g = 0; g < 8; ++g) s += prtA[g][tid];
    rq[blockIdx.x * 32 + tid] = (float)s;
    best[blockIdx.x * 32 + tid] = 0xFFFFFFFFFFFFFFFFULL;
  } else if (tid < 64) {
    double s = 0.0;
#pragma unroll
    for (int g = 0; g < 8; ++g) s += prtB[g][tid - 32];
    rp[blockIdx.x * 32 + (tid - 32)] = (float)s;
  }

  // coalesced wide stores: 32 points x 72 uint4 = 2304 = 9 x 256 per matrix
  uint4* gA = (uint4*)(Aext + (size_t)blockIdx.x * 32 * KE);
  uint4* gB = (uint4*)(Bext + (size_t)blockIdx.x * 32 * KE);
#pragma unroll
  for (int it = 0; it < 9; ++it) {
    int g = it * 256 + tid;
    int pp = g / 72;
    int cc = g - pp * 72;
    gA[g] = *(const uint4*)&bufA[pp * KEP + cc * 8];
    gB[g] = *(const uint4*)&bufB[pp * KEP + cc * 8];
  }
}

// --- MFMA GEMM: r13 structure + 32x32x16 shape w/ full-rank swizzle ----------
// LDS tile: 128 rows x 64 halves (8 slots of 16 B), single buffer (32 KB).
// Swizzle: logical slice L of row r lives at phys slot L ^ swz(r),
//   swz(r) = (r&7) ^ (((r>>3)&3)<<1).
// The extra (r>>3) term is what r8 lacked: lanes {m,m+8,m+16,m+24} (same
// logical, same m&7) now land on distinct phys slots -> distinct bank
// groups -> each 1 KB fragment read hits every bank exactly 8x (the
// minimum). Tile bases are multiples of 32 so swz depends only on m32.
// 32x32x16 MFMA: 24 mfma @8.07cyc vs 48 @4.85 per window (-17% MFMA pipe,
// m119) and 16 fewer resident fragment VGPRs (kills the (256,4) spill).
// C/D layout (m74/m101, r8-verified): col=lane&31, row=(reg&3)+8*(reg>>2)
// +4*(lane>>5). Supertile swizzle kept (r13: +8%).
__global__ __launch_bounds__(256, 4)
void gemm_argmin_kernel(const f16* __restrict__ A, const f16* __restrict__ B,
                        const float* __restrict__ rq,
                        unsigned long long* __restrict__ best) {
  __shared__ f16 Ash[128 * 64];   // 16 KB
  __shared__ f16 Bsh[128 * 64];   // 16 KB

  // ---- supertile swizzle: L -> (bx, by), 16x8 supertiles ----
  const int L  = blockIdx.x;          // 0..16383
  const int st = L >> 7;
  const int r  = L & 127;
  const int bx = ((st & 15) << 3) | (r & 7);
  const int by = ((st >> 4) << 4) | (r >> 3);

  const int nBase = bx * 128;
  const int mBase = by * 128;
  const f16* Ab = A + (size_t)mBase * KE;   // block-uniform -> SGPR pair
  const f16* Bb = B + (size_t)nBase * KE;
  const int t = threadIdx.x;
  const int w = t >> 6;           // wave 0..3
  const int l = t & 63;

  // ---- staging decode: per issue, 64 lanes cover 8 rows x 8 phys slots ----
  const int lr = l >> 3;                 // row within 8-row issue group
  const int lt = l & 7;                  // phys 16B slot
  // rows are w*32 + ig*8 + lr: (row>>3)&3 = ig, row&7 = lr
  // -> logical slice sl = lt ^ lr ^ (ig<<1)  (depends on ig: 4 variants)
  int rowHalf[4];                        // identical for A and B
#pragma unroll
  for (int ig = 0; ig < 4; ++ig) {
    int sl = lt ^ lr ^ ((ig & 3) << 1);
    int sColOff = (sl < 4) ? sl * 8 : KD + (sl & 3) * 8;
    rowHalf[ig] = (w * 32 + ig * 8 + lr) * KE + sColOff;
  }

  // ---- fragment decode (32x32x16): lane l holds M=m32, k-octet g ----
  const int m32 = l & 31;
  const int g   = l >> 5;                // 0..1
  const int swz = (m32 & 7) ^ (((m32 >> 3) & 3) << 1);
  const int wRow = (w & 1) * 64;
  const int wCol = (w >> 1) * 64;

  floatx16 acc[2][2] = {};

#pragma unroll
  for (int kw = 0; kw < NWIN; ++kw) {
    __syncthreads();                     // previous window's reads complete
#pragma unroll
    for (int ig = 0; ig < 4; ++ig)
      __builtin_amdgcn_global_load_lds(AS1(Ab + rowHalf[ig] + kw * 32),
                                       AS3(&Ash[(w * 32 + ig * 8) * 64]), 16, 0, 0);
#pragma unroll
    for (int ig = 0; ig < 4; ++ig)
      __builtin_amdgcn_global_load_lds(AS1(Bb + rowHalf[ig] + kw * 32),
                                       AS3(&Bsh[(w * 32 + ig * 8) * 64]), 16, 0, 0);
    __syncthreads();                     // staging drained

#pragma unroll
    for (int kh = 0; kh < 2; ++kh) {
      const int physHi = ((kh << 1) + g) ^ swz;        // hi logical 0..3
      const int physLo = (4 + (kh << 1) + g) ^ swz;    // lo logical 4..7
      const int offHi = m32 * 64 + physHi * 8;
      const int offLo = m32 * 64 + physLo * 8;

      half8 ah[2], al[2];
#pragma unroll
      for (int ti = 0; ti < 2; ++ti) {
        ah[ti] = *(const half8*)&Ash[(wRow + ti * 32) * 64 + offHi];
        al[ti] = *(const half8*)&Ash[(wRow + ti * 32) * 64 + offLo];
      }
      // stream bh: hi.hi + lo.hi
#pragma unroll
      for (int tj = 0; tj < 2; ++tj) {
        half8 bh = *(const half8*)&Bsh[(wCol + tj * 32) * 64 + offHi];
#pragma unroll
        for (int ti = 0; ti < 2; ++ti)
          acc[ti][tj] = __builtin_amdgcn_mfma_f32_32x32x16_f16(ah[ti], bh, acc[ti][tj], 0, 0, 0);
#pragma unroll
        for (int ti = 0; ti < 2; ++ti)
          acc[ti][tj] = __builtin_amdgcn_mfma_f32_32x32x16_f16(al[ti], bh, acc[ti][tj], 0, 0, 0);
      }
      // stream bl: hi.lo
#pragma unroll
      for (int tj = 0; tj < 2; ++tj) {
        half8 bl = *(const half8*)&Bsh[(wCol + tj * 32) * 64 + offLo];
#pragma unroll
        for (int ti = 0; ti < 2; ++ti)
          acc[ti][tj] = __builtin_amdgcn_mfma_f32_32x32x16_f16(ah[ti], bl, acc[ti][tj], 0, 0, 0);
      }
    }
  }

  // ---- epilogue: f = rq[col] - 2*dot, packed argmin ----
  // C/D 32x32: col = lane&31, row = (reg&3) + 8*(reg>>2) + 4*g
  const int colBase = nBase + wCol + m32;
  float rqv[2] = { rq[colBase], rq[colBase + 32] };

#pragma unroll
  for (int ti = 0; ti < 2; ++ti) {
#pragma unroll
    for (int reg = 0; reg < 16; ++reg) {
      const int rowG = mBase + wRow + ti * 32 + (reg & 3) + 8 * (reg >> 2) + 4 * g;
      float f0 = fmaf(-2.0f, acc[ti][0][reg], rqv[0]);
      unsigned int b0 = __float_as_uint(f0);
      b0 = (b0 & 0x80000000u) ? ~b0 : (b0 | 0x80000000u);
      unsigned long long pk =
          ((unsigned long long)b0 << 32) | (unsigned)colBase;
      float f1 = fmaf(-2.0f, acc[ti][1][reg], rqv[1]);
      unsigned int b1 = __float_as_uint(f1);
      b1 = (b1 & 0x80000000u) ? ~b1 : (b1 | 0x80000000u);
      unsigned long long c1 =
          ((unsigned long long)b1 << 32) | (unsigned)(colBase + 32);
      pk = pk < c1 ? pk : c1;
#pragma unroll
      for (int s = 1; s < 32; s <<= 1) {
        unsigned long long o = __shfl_xor(pk, s, 32);
        pk = pk < o ? pk : o;
      }
      if (m32 == 0) atomicMin(best + rowG, pk);
    }
  }
}

// ---------------------------- finalize ---------------------------------------
__global__ void finalize_kernel(const unsigned long long* __restrict__ best,
                                const float* __restrict__ rp,
                                float* __restrict__ out) {
  int i = blockIdx.x * 256 + threadIdx.x;
  if (i >= NPT) return;
  unsigned long long v = best[i];
  unsigned int col = (unsigned int)(v & 0xFFFFFFFFu);
  unsigned int key = (unsigned int)(v >> 32);
  unsigned int bits = (key & 0x80000000u) ? (key & 0x7FFFFFFFu) : ~key;
  float fmin = __uint_as_float(bits);
  out[i]           = (float)(col >> 7);   // idy
  out[NPT + i]     = (float)(col & 127);  // idx
  out[2 * NPT + i] = rp[i] + fmin;        // nnd
}

extern "C" void kernel_launch(void* const* d_in, const int* in_sizes, int n_in,
                              void* d_out, int out_size, void* d_ws, size_t ws_size,
                              hipStream_t stream) {
  const float* src = (const float*)d_in[0];  // source_map (1,32,128,128)
  const float* tgt = (const float*)d_in[1];  // target_map (1,32,128,128)
  float* out = (float*)d_out;

  // workspace layout (bytes):
  //   Aext: [0, 18874368)        16384 x 576 f16 (point-major [hi|lo])
  //   Bext: [18874368, 37748736)
  //   rq  : [37748736, 37814272) 16384 fp32
  //   rp  : [37814272, 37879808)
  //   best: [37879808, 38010880) 16384 u64 packed (key<<32)|col
  char* ws = (char*)d_ws;
  f16* Aext = (f16*)(ws);
  f16* Bext = (f16*)(ws + 18874368);
  float* rq = (float*)(ws + 37748736);
  float* rp = (float*)(ws + 37814272);
  unsigned long long* best = (unsigned long long*)(ws + 37879808);

  extract_split_kernel<<<NPT / 32, 256, 0, stream>>>(src, tgt, Aext, Bext,
                                                     rq, rp, best);
  gemm_argmin_kernel<<<16384, 256, 0, stream>>>(Aext, Bext, rq, best);
  finalize_kernel<<<NPT / 256, 256, 0, stream>>>(best, rp, out);
}

// Round 18
// 542.809 us; speedup vs baseline: 1.1904x; 1.1904x over previous
//
#include <hip/hip_runtime.h>
#include <stdint.h>

// Problem constants (n=1, c=32, h=w=128, p=3)
#define NPT    16384        // points (h*w)
#define KD     288          // c*p*p
#define KE     576          // per-point row: [hi(288) | lo(288)] f16
#define KEP    584          // padded LDS row (extract): bank stride 4 -> 4-way
#define NWIN   9            // 9 merged K-windows of 32 (hi+lo staged together)

typedef _Float16 f16;
typedef __attribute__((ext_vector_type(8))) _Float16 half8;
typedef __attribute__((ext_vector_type(4))) float floatx4;

#define AS1(p) ((const __attribute__((address_space(1))) uint32_t*)(p))
#define AS3(p) ((__attribute__((address_space(3))) uint32_t*)(p))

// -------- patch extraction + fp32->2xf16 split + fused norms/init ------------
// r17-measured: KEP padding takes the LDS store pattern from 32-way conflicts
// (1152 B row stride = bank 0 for all rows) to 4-way -> extract ~58 -> ~5 us.
__global__ __launch_bounds__(256)
void extract_split_kernel(const float* __restrict__ src,
                          const float* __restrict__ tgt,
                          f16* __restrict__ Aext,
                          f16* __restrict__ Bext,
                          float* __restrict__ rq,
                          float* __restrict__ rp,
                          unsigned long long* __restrict__ best) {
  __shared__ f16 bufA[32 * KEP];      // 36.5 KB
  __shared__ f16 bufB[32 * KEP];      // 36.5 KB
  __shared__ double prtA[8][32];
  __shared__ double prtB[8][32];

  const int tid = threadIdx.x;
  const int p  = tid & 31;            // local point
  const int cg = tid >> 5;            // channel group 0..7
  const int point = blockIdx.x * 32 + p;
  const int y = point >> 7, x = point & 127;

  double sq = 0.0, sp_ = 0.0;
#pragma unroll
  for (int cc = 0; cc < 4; ++cc) {
    const int c = cg * 4 + cc;
#pragma unroll
    for (int dy = 0; dy < 3; ++dy) {
      int yy = y + dy - 1; yy = yy < 0 ? 0 : (yy > 127 ? 127 : yy);
#pragma unroll
      for (int dx = 0; dx < 3; ++dx) {
        int xx = x + dx - 1; xx = xx < 0 ? 0 : (xx > 127 ? 127 : xx);
        const int k = c * 9 + dy * 3 + dx;
        const int m = (c << 14) + (yy << 7) + xx;
        float v = src[m];
        sq += (double)v * (double)v;
        f16 h = (f16)v;
        bufA[p * KEP + k] = h;
        bufA[p * KEP + KD + k] = (f16)(v - (float)h);
        v = tgt[m];
        sp_ += (double)v * (double)v;
        h = (f16)v;
        bufB[p * KEP + k] = h;
        bufB[p * KEP + KD + k] = (f16)(v - (float)h);
      }
    }
  }
  prtA[cg][p] = sq;
  prtB[cg][p] = sp_;
  __syncthreads();

  if (tid < 32) {
    double s = 0.0;
#pragma unroll
    for (int g = 0; g < 8; ++g) s += prtA[g][tid];
    rq[blockIdx.x * 32 + tid] = (float)s;
    best[blockIdx.x * 32 + tid] = 0xFFFFFFFFFFFFFFFFULL;
  } else if (tid < 64) {
    double s = 0.0;
#pragma unroll
    for (int g = 0; g < 8; ++g) s += prtB[g][tid - 32];
    rp[blockIdx.x * 32 + (tid - 32)] = (float)s;
  }

  // coalesced wide stores: 32 points x 72 uint4 = 2304 = 9 x 256 per matrix
  uint4* gA = (uint4*)(Aext + (size_t)blockIdx.x * 32 * KE);
  uint4* gB = (uint4*)(Bext + (size_t)blockIdx.x * 32 * KE);
#pragma unroll
  for (int it = 0; it < 9; ++it) {
    int g = it * 256 + tid;
    int pp = g / 72;
    int cc = g - pp * 72;
    gA[g] = *(const uint4*)&bufA[pp * KEP + cc * 8];
    gB[g] = *(const uint4*)&bufB[pp * KEP + cc * 8];
  }
}

// --- MFMA GEMM: r13 champion verbatim (measured 478 us, MfmaUtil 46.5%) ------
// 128x128 tile, 16x16x32 path (measured 0 bank conflicts), merged [hi|lo]
// windows (2 barriers/window), slim fragment plan (ah/al resident, b
// streamed) under __launch_bounds__(256,4) -> 4 blocks/CU, and the 16x8
// supertile XCD swizzle (staging rides per-XCD L2, +8%). All structural
// alternatives measured worse: dbuf (r3/r9), register relay (r11),
// producer/consumer (r14), LDS-free (r15), 256x128 (r16), 32x32 (r8/r17).
__global__ __launch_bounds__(256, 4)
void gemm_argmin_kernel(const f16* __restrict__ A, const f16* __restrict__ B,
                        const float* __restrict__ rq,
                        unsigned long long* __restrict__ best) {
  __shared__ f16 Ash[128 * 64];   // 16 KB
  __shared__ f16 Bsh[128 * 64];   // 16 KB

  // ---- supertile swizzle: L -> (bx, by), 16x8 supertiles ----
  const int L  = blockIdx.x;          // 0..16383
  const int st = L >> 7;
  const int r  = L & 127;
  const int bx = ((st & 15) << 3) | (r & 7);
  const int by = ((st >> 4) << 4) | (r >> 3);

  const int nBase = bx * 128;
  const int mBase = by * 128;
  const f16* Ab = A + (size_t)mBase * KE;   // block-uniform -> SGPR pair
  const f16* Bb = B + (size_t)nBase * KE;
  const int t = threadIdx.x;
  const int w = t >> 6;           // wave 0..3
  const int l = t & 63;

  // ---- staging decode: per issue, 64 lanes cover 8 rows x 8 phys slots ----
  const int lr = l >> 3;                 // row within 8-row issue group
  const int lt = l & 7;                  // phys 16B slot
  const int sl = lt ^ (lr & 7);          // logical slice this lane fetches
  const int sColOff = (sl < 4) ? sl * 8 : KD + (sl & 3) * 8;  // + kw*32/window
  int rowHalf[4];                        // identical for A and B
#pragma unroll
  for (int ig = 0; ig < 4; ++ig)
    rowHalf[ig] = (w * 32 + ig * 8 + lr) * KE + sColOff;

  // ---- fragment decode (16x16x32) ----
  const int m16 = l & 15;
  const int q   = l >> 4;                // k-quad
  const int pHi = q ^ (m16 & 7);         // phys slot of hi octet q
  const int pLo = pHi ^ 4;               // phys slot of lo octet q
  const int wRow = (w & 1) * 64;
  const int wCol = (w >> 1) * 64;
  const int aHiOff = m16 * 64 + pHi * 8;
  const int aLoOff = m16 * 64 + pLo * 8;

  floatx4 acc[4][4] = {};

#pragma unroll
  for (int kw = 0; kw < NWIN; ++kw) {
    __syncthreads();                     // previous window's reads complete
#pragma unroll
    for (int ig = 0; ig < 4; ++ig)
      __builtin_amdgcn_global_load_lds(AS1(Ab + rowHalf[ig] + kw * 32),
                                       AS3(&Ash[(w * 32 + ig * 8) * 64]), 16, 0, 0);
#pragma unroll
    for (int ig = 0; ig < 4; ++ig)
      __builtin_amdgcn_global_load_lds(AS1(Bb + rowHalf[ig] + kw * 32),
                                       AS3(&Bsh[(w * 32 + ig * 8) * 64]), 16, 0, 0);
    __syncthreads();                     // staging drained

    // resident A fragments (hi + lo); stream B fragments one tile at a time
    half8 ah[4], al[4];
#pragma unroll
    for (int i = 0; i < 4; ++i) {
      ah[i] = *(const half8*)&Ash[(wRow + i * 16) * 64 + aHiOff];
      al[i] = *(const half8*)&Ash[(wRow + i * 16) * 64 + aLoOff];
    }
#pragma unroll
    for (int j = 0; j < 4; ++j) {
      half8 bh = *(const half8*)&Bsh[(wCol + j * 16) * 64 + aHiOff];
#pragma unroll
      for (int i = 0; i < 4; ++i)
        acc[i][j] = __builtin_amdgcn_mfma_f32_16x16x32_f16(ah[i], bh, acc[i][j], 0, 0, 0);
#pragma unroll
      for (int i = 0; i < 4; ++i)
        acc[i][j] = __builtin_amdgcn_mfma_f32_16x16x32_f16(al[i], bh, acc[i][j], 0, 0, 0);
    }
#pragma unroll
    for (int j = 0; j < 4; ++j) {
      half8 bl = *(const half8*)&Bsh[(wCol + j * 16) * 64 + aLoOff];
#pragma unroll
      for (int i = 0; i < 4; ++i)
        acc[i][j] = __builtin_amdgcn_mfma_f32_16x16x32_f16(ah[i], bl, acc[i][j], 0, 0, 0);
    }
  }

  // ---- epilogue: f = rq[col] - 2*dot, packed argmin ----
  // C/D layout (16x16): col = lane&15, row = (lane>>4)*4 + reg
  const int colBase = nBase + wCol + m16;
  float rqv[4];
#pragma unroll
  for (int j = 0; j < 4; ++j) rqv[j] = rq[colBase + j * 16];

#pragma unroll
  for (int i = 0; i < 4; ++i) {
    const int rowB = mBase + wRow + i * 16 + q * 4;
#pragma unroll
    for (int r2 = 0; r2 < 4; ++r2) {
      unsigned long long pk = 0xFFFFFFFFFFFFFFFFULL;
#pragma unroll
      for (int j = 0; j < 4; ++j) {
        float f = fmaf(-2.0f, acc[i][j][r2], rqv[j]);
        unsigned int bits = __float_as_uint(f);
        unsigned int key = (bits & 0x80000000u) ? ~bits : (bits | 0x80000000u);
        unsigned long long cand =
            ((unsigned long long)key << 32) | (unsigned)(colBase + j * 16);
        pk = pk < cand ? pk : cand;
      }
#pragma unroll
      for (int sft = 1; sft < 16; sft <<= 1) {
        unsigned long long o = __shfl_xor(pk, sft, 16);
        pk = pk < o ? pk : o;
      }
      if (m16 == 0) atomicMin(best + rowB + r2, pk);
    }
  }
}

// ---------------------------- finalize ---------------------------------------
__global__ void finalize_kernel(const unsigned long long* __restrict__ best,
                                const float* __restrict__ rp,
                                float* __restrict__ out) {
  int i = blockIdx.x * 256 + threadIdx.x;
  if (i >= NPT) return;
  unsigned long long v = best[i];
  unsigned int col = (unsigned int)(v & 0xFFFFFFFFu);
  unsigned int key = (unsigned int)(v >> 32);
  unsigned int bits = (key & 0x80000000u) ? (key & 0x7FFFFFFFu) : ~key;
  float fmin = __uint_as_float(bits);
  out[i]           = (float)(col >> 7);   // idy
  out[NPT + i]     = (float)(col & 127);  // idx
  out[2 * NPT + i] = rp[i] + fmin;        // nnd
}

extern "C" void kernel_launch(void* const* d_in, const int* in_sizes, int n_in,
                              void* d_out, int out_size, void* d_ws, size_t ws_size,
                              hipStream_t stream) {
  const float* src = (const float*)d_in[0];  // source_map (1,32,128,128)
  const float* tgt = (const float*)d_in[1];  // target_map (1,32,128,128)
  float* out = (float*)d_out;

  // workspace layout (bytes):
  //   Aext: [0, 18874368)        16384 x 576 f16 (point-major [hi|lo])
  //   Bext: [18874368, 37748736)
  //   rq  : [37748736, 37814272) 16384 fp32
  //   rp  : [37814272, 37879808)
  //   best: [37879808, 38010880) 16384 u64 packed (key<<32)|col
  char* ws = (char*)d_ws;
  f16* Aext = (f16*)(ws);
  f16* Bext = (f16*)(ws + 18874368);
  float* rq = (float*)(ws + 37748736);
  float* rp = (float*)(ws + 37814272);
  unsigned long long* best = (unsigned long long*)(ws + 37879808);

  extract_split_kernel<<<NPT / 32, 256, 0, stream>>>(src, tgt, Aext, Bext,
                                                     rq, rp, best);
  gemm_argmin_kernel<<<16384, 256, 0, stream>>>(Aext, Bext, rq, best);
  finalize_kernel<<<NPT / 256, 256, 0, stream>>>(best, rp, out);
}